// Round 1
// baseline (269.439 us; speedup 1.0000x reference)
//
#include <hip/hip_runtime.h>

#define D 8

// R1 theory: measured 259 µs = harness re-poison fills (~205 µs, visible as
// fillBufferAligned @ ~6.5 TB/s in rocprof) + ~54 µs ours. Of ours, ~45 µs was
// fused_out streaming 256 MiB of mostly-zeros. Replace it with a hipMemsetAsync
// node (rocclr fill path, measured 6.5-6.7 TB/s on this chip) + a compact
// scatter over claimed tiles only (~8 MiB). zero_ws also becomes a memset.

// ---------- Plan A: claim table in d_ws ----------

__global__ void claim_ws_kernel(const int* __restrict__ src,
                                const int* __restrict__ dst,
                                int* __restrict__ ws, int n, int e) {
    int k = blockIdx.x * blockDim.x + threadIdx.x;
    if (k >= e) return;
    atomicMax(&ws[src[k] * n + dst[k]], k + 1);  // last edge wins (numpy semantics)
}

// 16 threads per edge; only the winning edge writes its 8x8 tile (4 floats/thread,
// 256 B contiguous per 16 lanes).
__global__ void scatter_claimed_kernel(const float* __restrict__ x,
                                       const int* __restrict__ src,
                                       const int* __restrict__ dst,
                                       const float* __restrict__ W,
                                       const int* __restrict__ ws,
                                       float4* __restrict__ out4,
                                       int n, int e) {
    int gid = blockIdx.x * blockDim.x + threadIdx.x;
    int k = gid >> 4;
    int t = gid & 15;
    if (k >= e) return;
    int s = src[k], d = dst[k];
    int tile = s * n + d;
    if (ws[tile] != k + 1) return;  // a later duplicate edge owns this tile

    const float* xs = x + s * D;
    const float* xd = x + d * D;
    float diff[D];
#pragma unroll
    for (int i = 0; i < D; ++i) diff[i] = fabsf(xs[i] - xd[i]);

    float acc[4];
#pragma unroll
    for (int j = 0; j < 4; ++j) {
        int o = t * 4 + j;
        const float* w = W + o * D;
        float a = 0.f;
#pragma unroll
        for (int i = 0; i < D; ++i) a += diff[i] * w[i];
        acc[j] = a;
    }
    float4 r;
    r.x = acc[0]; r.y = acc[1]; r.z = acc[2]; r.w = acc[3];
    out4[(size_t)tile * 16 + t] = r;
}

// ---------- Plan B fallback (ws too small): claim slot lives in d_out ----------

__global__ void claim_out_kernel(const int* __restrict__ src,
                                 const int* __restrict__ dst,
                                 int* __restrict__ out_i, int n, int e) {
    int k = blockIdx.x * blockDim.x + threadIdx.x;
    if (k >= e) return;
    long long pair = (long long)src[k] * n + dst[k];
    atomicMax(&out_i[pair * 64], k + 1);
}

__global__ void scatter_out_kernel(const float* __restrict__ x,
                                   const int* __restrict__ src,
                                   const int* __restrict__ dst,
                                   const float* __restrict__ W,
                                   float* __restrict__ out, int n, int e) {
    int gid = blockIdx.x * blockDim.x + threadIdx.x;
    int k = gid >> 6;
    int o = gid & 63;
    if (k >= e) return;
    int s = src[k], d = dst[k];
    long long base = ((long long)s * n + d) * 64;
    int claim = __float_as_int(out[base]);
    if (claim != k + 1) return;
    const float* xs = x + s * D;
    const float* xd = x + d * D;
    const float* w = W + o * D;
    float a = 0.f;
#pragma unroll
    for (int i = 0; i < D; ++i) a += fabsf(xs[i] - xd[i]) * w[i];
    out[base + o] = a;
}

extern "C" void kernel_launch(void* const* d_in, const int* in_sizes, int n_in,
                              void* d_out, int out_size, void* d_ws, size_t ws_size,
                              hipStream_t stream) {
    const float* x  = (const float*)d_in[0];
    const int*   ei = (const int*)d_in[1];   // [2, e]: src row then dst row (int32)
    const float* W  = (const float*)d_in[2]; // [64, 8] row-major

    int n = in_sizes[0] / D;   // 1024
    int e = in_sizes[1] / 2;   // 32768
    const int* src = ei;
    const int* dst = ei + e;

    int ntiles = out_size / 64;                          // n*n (out_size in elements)
    size_t out_bytes = (size_t)out_size * sizeof(float); // 256 MiB

    if (ws_size >= (size_t)ntiles * sizeof(int)) {
        int* ws = (int*)d_ws;
        // Bulk zeros at rocclr fill rate (~6.5 TB/s measured on this chip).
        hipMemsetAsync(d_out, 0, out_bytes, stream);
        hipMemsetAsync(ws, 0, (size_t)ntiles * sizeof(int), stream);
        {
            int threads = 256, blocks = (e + threads - 1) / threads;
            claim_ws_kernel<<<blocks, threads, 0, stream>>>(src, dst, ws, n, e);
        }
        {
            int threads = 256;
            int total = e * 16;                          // 524288
            int blocks = (total + threads - 1) / threads;
            scatter_claimed_kernel<<<blocks, threads, 0, stream>>>(
                x, src, dst, W, ws, (float4*)d_out, n, e);
        }
    } else {
        hipMemsetAsync(d_out, 0, out_bytes, stream);
        {
            int threads = 256, blocks = (e + threads - 1) / threads;
            claim_out_kernel<<<blocks, threads, 0, stream>>>(src, dst, (int*)d_out, n, e);
        }
        {
            int threads = 256;
            long long total = (long long)e * 64;
            int blocks = (int)((total + threads - 1) / threads);
            scatter_out_kernel<<<blocks, threads, 0, stream>>>(
                x, src, dst, W, (float*)d_out, n, e);
        }
    }
}

// Round 3
// 263.163 us; speedup vs baseline: 1.0238x; 1.0238x over previous
//
#include <hip/hip_runtime.h>

#define D 8

// R3: R2 structure with the compile fix — __builtin_nontemporal_store requires
// a native clang vector type, not HIP_vector_type<float,4>. Use
// ext_vector_type(4) float for the output stores.
// Budget model: dur = ~205 µs harness poison (visible as fillBufferAligned in
// rocprof) + ours (zero_ws ~1.3 µs + claim ~2 µs + fused 256 MiB single-pass).

typedef float vfloat4 __attribute__((ext_vector_type(4)));

// ---------- Plan A: claim table in d_ws, single-pass output ----------

__global__ void zero_ws_kernel(int4* __restrict__ ws4, int n16) {
    int i = blockIdx.x * blockDim.x + threadIdx.x;
    if (i < n16) ws4[i] = make_int4(0, 0, 0, 0);
}

__global__ void claim_ws_kernel(const int* __restrict__ src,
                                const int* __restrict__ dst,
                                int* __restrict__ ws, int n, int e) {
    int k = blockIdx.x * blockDim.x + threadIdx.x;
    if (k >= e) return;
    atomicMax(&ws[src[k] * n + dst[k]], k + 1);  // last edge wins (numpy semantics)
}

// One vfloat4 (4 output elems) per thread; 16 threads cover one 8x8 tile.
// Wave = 4 consecutive tiles = 1 KiB contiguous nontemporal stores.
__global__ void fused_out_kernel(const float* __restrict__ x,
                                 const int* __restrict__ src,
                                 const int* __restrict__ dst,
                                 const float* __restrict__ W,
                                 const int* __restrict__ ws,
                                 vfloat4* __restrict__ out4,
                                 int ntiles) {
    int gid = blockIdx.x * blockDim.x + threadIdx.x;
    int tile = gid >> 4;
    int t = gid & 15;
    if (tile >= ntiles) return;

    int claim = ws[tile];
    if (claim == 0) {
        vfloat4 z = {0.f, 0.f, 0.f, 0.f};
        __builtin_nontemporal_store(z, &out4[gid]);
        return;
    }
    int k = claim - 1;
    int s = src[k], d = dst[k];
    const float* xs = x + s * D;
    const float* xd = x + d * D;

    float diff[D];
#pragma unroll
    for (int i = 0; i < D; ++i) diff[i] = fabsf(xs[i] - xd[i]);

    vfloat4 r;
#pragma unroll
    for (int j = 0; j < 4; ++j) {
        int o = t * 4 + j;
        const float* w = W + o * D;
        float a = 0.f;
#pragma unroll
        for (int i = 0; i < D; ++i) a += diff[i] * w[i];
        r[j] = a;
    }
    __builtin_nontemporal_store(r, &out4[gid]);
}

// ---------- Plan B fallback (ws too small): claim slot lives in d_out ----------

__global__ void zero_out_kernel(float4* __restrict__ out4, int n4) {
    int i = blockIdx.x * blockDim.x + threadIdx.x;
    if (i < n4) out4[i] = make_float4(0.f, 0.f, 0.f, 0.f);
}

__global__ void claim_out_kernel(const int* __restrict__ src,
                                 const int* __restrict__ dst,
                                 int* __restrict__ out_i, int n, int e) {
    int k = blockIdx.x * blockDim.x + threadIdx.x;
    if (k >= e) return;
    long long pair = (long long)src[k] * n + dst[k];
    atomicMax(&out_i[pair * 64], k + 1);
}

__global__ void scatter_out_kernel(const float* __restrict__ x,
                                   const int* __restrict__ src,
                                   const int* __restrict__ dst,
                                   const float* __restrict__ W,
                                   float* __restrict__ out, int n, int e) {
    int gid = blockIdx.x * blockDim.x + threadIdx.x;
    int k = gid >> 6;
    int o = gid & 63;
    if (k >= e) return;
    int s = src[k], d = dst[k];
    long long base = ((long long)s * n + d) * 64;
    int claim = __float_as_int(out[base]);
    if (claim != k + 1) return;
    const float* xs = x + s * D;
    const float* xd = x + d * D;
    const float* w = W + o * D;
    float a = 0.f;
#pragma unroll
    for (int i = 0; i < D; ++i) a += fabsf(xs[i] - xd[i]) * w[i];
    out[base + o] = a;
}

extern "C" void kernel_launch(void* const* d_in, const int* in_sizes, int n_in,
                              void* d_out, int out_size, void* d_ws, size_t ws_size,
                              hipStream_t stream) {
    const float* x  = (const float*)d_in[0];
    const int*   ei = (const int*)d_in[1];   // [2, e]: src row then dst row
    const float* W  = (const float*)d_in[2]; // [64, 8] row-major

    int n = in_sizes[0] / D;   // 1024
    int e = in_sizes[1] / 2;   // 32768
    const int* src = ei;
    const int* dst = ei + e;

    int ntiles = out_size / 64;            // n*n
    int n4 = out_size / 4;                 // float4 count

    if (ws_size >= (size_t)ntiles * sizeof(int)) {
        int* ws = (int*)d_ws;
        {
            int n16 = ntiles / 4;  // ntiles is n*n, divisible by 4
            int threads = 256, blocks = (n16 + threads - 1) / threads;
            zero_ws_kernel<<<blocks, threads, 0, stream>>>((int4*)ws, n16);
        }
        {
            int threads = 256, blocks = (e + threads - 1) / threads;
            claim_ws_kernel<<<blocks, threads, 0, stream>>>(src, dst, ws, n, e);
        }
        {
            int threads = 256;
            long long total = (long long)ntiles * 16;
            int blocks = (int)((total + threads - 1) / threads);
            fused_out_kernel<<<blocks, threads, 0, stream>>>(
                x, src, dst, W, ws, (vfloat4*)d_out, ntiles);
        }
    } else {
        {
            int threads = 256, blocks = (n4 + threads - 1) / threads;
            zero_out_kernel<<<blocks, threads, 0, stream>>>((float4*)d_out, n4);
        }
        {
            int threads = 256, blocks = (e + threads - 1) / threads;
            claim_out_kernel<<<blocks, threads, 0, stream>>>(src, dst, (int*)d_out, n, e);
        }
        {
            int threads = 256;
            long long total = (long long)e * 64;
            int blocks = (int)((total + threads - 1) / threads);
            scatter_out_kernel<<<blocks, threads, 0, stream>>>(
                x, src, dst, W, (float*)d_out, n, e);
        }
    }
}